// Round 11
// baseline (52.253 us; speedup 1.0000x reference)
//
#include <hip/hip_runtime.h>

#define NQ    12
#define BATCH 8192

typedef float v2f __attribute__((ext_vector_type(2)));

// ---------------------------------------------------------------------------
// One wave = one batch element's 4096-dim real state (imag identically 0).
// Layout A: lane bits = qubits 6..11, reg bits = qubits 0..5
// Layout B: lane bits = qubits 0..5,  reg bits = qubits 6..11
// Per layer: 6 reg-gates, LDS transpose, 6 reg-gates, ring boundary CNOTs;
// ring renamings (sig powers) deferred via compile-time index renaming.
// RY in tan form (G = prod cos folded into epilogue as G^2); state float2[32],
// gates via v_pk_fma_f32.
// Transpose: 4-phase quadrant staging, pair-slot layout
//   slot(rr,rho) = (rr>>1)*66 + 2*rho + (rr&1) words, rr = local reg row 0..31.
//   Phase (p,q): writer half p publishes regs [32q,32q+32) as 16 ds_write_b64;
//   readers j in [32q,32q+32) fetch 16 new-reg pairs via ds_read2_b32.
//   Buffer = 1056 words = 4224 B/wave (8448 B/block) -> occupancy cap moves
//   from LDS (4.8 waves/SIMD) to VGPR (7 waves/SIMD).
//   Cross-phase slot reuse is safe: same-wave DS ops execute in order.
// ---------------------------------------------------------------------------

constexpr int sig6(int x)            { return (x ^ (x << 1)) & 63; }
constexpr int sigpow6(int x, int t)  { return t == 0 ? x : sigpow6(sig6(x), t - 1); }
constexpr int rowmask6(int j, int t) {        // bit_j(sig^-t(p)) = par(p & m)
    int tt = (8 - (t % 8)) % 8;
    int m = 0;
    for (int i = 0; i < 6; ++i)
        if ((sigpow6(1 << i, tt) >> j) & 1) m |= 1 << i;
    return m;
}
constexpr bool par6(int x) { return (__builtin_popcount(x & 63) & 1) != 0; }

#define VAT(w, i) w[(i) >> 1][(i) & 1]

// ---- cross-lane helpers ---------------------------------------------------
template<int C>
__device__ __forceinline__ float dppf(float x) {
    return __int_as_float(__builtin_amdgcn_mov_dpp(__float_as_int(x), C, 0xF, 0xF, true));
}

template<int M>
__device__ __forceinline__ float shx(float x) {
    static_assert(M > 0 && M < 64, "mask");
    constexpr int lo = M & 31;
    float y = x;
    if constexpr (lo == 1)       y = dppf<0xB1>(y);
    else if constexpr (lo == 2)  y = dppf<0x4E>(y);
    else if constexpr (lo == 3)  y = dppf<0x1B>(y);
    else if constexpr (lo == 7)  y = dppf<0x141>(y);
    else if constexpr (lo == 15) y = dppf<0x140>(y);
    else if constexpr (lo != 0)
        y = __int_as_float(__builtin_amdgcn_ds_swizzle(__float_as_int(y),
                                                       0x1F | (lo << 10)));
    if constexpr ((M & 32) != 0) {
        int yi = __float_as_int(y);
        auto p = __builtin_amdgcn_permlane32_swap(yi, yi, false, false);
        y = (__int_as_float(p[0]) + __int_as_float(p[1])) - y;
    }
    return y;
}

// signed butterfly: returns sum_l (-1)^par(l&M) x_l (writing lanes 0..11 all
// sign-positive).
template<int M>
__device__ __forceinline__ float wave_red(float x) {
    { float o = dppf<0xB1>(x); x = (M & 1)  ? x - o : x + o; }
    { float o = dppf<0x4E>(x); x = (M & 2)  ? x - o : x + o; }
    { float o = __int_as_float(__builtin_amdgcn_ds_swizzle(__float_as_int(x), 0x1F | (4  << 10))); x = (M & 4)  ? x - o : x + o; }
    { float o = __int_as_float(__builtin_amdgcn_ds_swizzle(__float_as_int(x), 0x1F | (8  << 10))); x = (M & 8)  ? x - o : x + o; }
    { float o = __int_as_float(__builtin_amdgcn_ds_swizzle(__float_as_int(x), 0x1F | (16 << 10))); x = (M & 16) ? x - o : x + o; }
    int xi = __float_as_int(x);
    auto p = __builtin_amdgcn_permlane32_swap(xi, xi, false, false);
    float s = __int_as_float(p[0]) + __int_as_float(p[1]);
    return (M & 32) ? (2.0f * x - s) : s;
}

// ---- packed tan-form RY on reg qubit-bit Q, renaming sig^T ----------------
template<int T, int Q>
__device__ __forceinline__ void regRY(v2f* w, float t) {
    constexpr int D = sigpow6(1 << Q, T);   // physical partner xor
    const v2f tMM = {-t, -t}, tPP = {t, t}, tMP = {-t, t}, tPM = {t, -t};
    if constexpr (Q == 0) {
        constexpr int K = D >> 1;           // D odd: comp-swapped partner
        #pragma unroll
        for (int k = 0; k < 32; ++k) {
            const int k2 = k ^ K;
            if (k2 < k) continue;
            v2f a = w[k], b = w[k2];
            v2f sb = {b[1], b[0]}, sa = {a[1], a[0]};
            w[k]  = __builtin_elementwise_fma(tMP, sb, a);
            w[k2] = __builtin_elementwise_fma(tMP, sa, b);
        }
    } else {
        constexpr int K  = D >> 1;          // D even: comps aligned
        constexpr int RM = rowmask6(Q, T);
        #pragma unroll
        for (int k = 0; k < 32; ++k) {
            const int k2 = k ^ K;
            if (k2 < k) continue;
            const bool p = par6((2 * k) & RM);
            if constexpr (RM & 1) {
                v2f a = w[k], b = w[k2];
                const v2f tk  = p ? tPM : tMP;
                const v2f tk2 = p ? tMP : tPM;
                w[k]  = __builtin_elementwise_fma(tk,  b, a);
                w[k2] = __builtin_elementwise_fma(tk2, a, b);
            } else {
                if (p) {
                    v2f a = w[k2], b = w[k];
                    w[k2] = __builtin_elementwise_fma(tMM, b, a);
                    w[k]  = __builtin_elementwise_fma(tPP, a, b);
                } else {
                    v2f a = w[k], b = w[k2];
                    w[k]  = __builtin_elementwise_fma(tMM, b, a);
                    w[k2] = __builtin_elementwise_fma(tPP, a, b);
                }
            }
        }
    }
}

// ---- ring boundary CNOTs --------------------------------------------------
template<int T>          // layout A CNOT(5,6): reg bit5 controls lane xor
__device__ __forceinline__ void c56A(v2f* w) {
    constexpr int ML = sigpow6(1, T);
    #pragma unroll
    for (int r = 32; r < 64; ++r) {
        const int pr = sigpow6(r, T + 1);
        VAT(w, pr) = shx<ML>(VAT(w, pr));
    }
}
template<int T>          // layout A CNOT(11,0): lane bit5 controls reg swap
__device__ __forceinline__ void c110A(v2f* w, int lane) {
    const bool cond = par6(lane & rowmask6(5, T + 1));
    constexpr int D = sigpow6(1, T + 1);
    #pragma unroll
    for (int r0 = 0; r0 < 64; r0 += 2) {
        const int a0 = sigpow6(r0, T + 1);
        const int a1 = a0 ^ D;
        float x0 = VAT(w, a0), x1 = VAT(w, a1);
        VAT(w, a0) = cond ? x1 : x0;
        VAT(w, a1) = cond ? x0 : x1;
    }
}
template<int T>          // layout B CNOT(5,6): lane bit5 controls reg swap
__device__ __forceinline__ void c56B(v2f* w, int lane) {
    const bool cond = par6(lane & rowmask6(5, T + 1));
    constexpr int D = sigpow6(1, T);
    #pragma unroll
    for (int r0 = 0; r0 < 64; r0 += 2) {
        const int a0 = sigpow6(r0, T);
        const int a1 = a0 ^ D;
        float x0 = VAT(w, a0), x1 = VAT(w, a1);
        VAT(w, a0) = cond ? x1 : x0;
        VAT(w, a1) = cond ? x0 : x1;
    }
}
template<int T>          // layout B CNOT(11,0): reg bit5 controls lane xor
__device__ __forceinline__ void c110B(v2f* w) {
    constexpr int ML = sigpow6(1, T + 1);
    #pragma unroll
    for (int r = 32; r < 64; ++r) {
        const int pr = sigpow6(r, T + 1);
        VAT(w, pr) = shx<ML>(VAT(w, pr));
    }
}
template<int T>
__device__ __forceinline__ void ringA(v2f* w, int lane) { c56A<T>(w); c110A<T>(w, lane); }
template<int T>
__device__ __forceinline__ void ringB(v2f* w, int lane) { c56B<T>(w, lane); c110B<T>(w); }

// ---- lane<->reg transpose, 4-phase quadrant staging (S = 66) --------------
// Phase (p,q): writer lanes with (lane>=32)==p publish regs [32q,32q+32) as
// 16 ds_write_b64 at dword k*66 + 2*(lane&31); reader lanes j in [32q,32q+32)
// fetch new reg pairs (32p+2k, 32p+2k+1) via ds_read2_b32 at base
// (rr>>1)*66 + (rr&1), dword offsets {4k, 4k+2}, rr = j&31.
// Hazard audit: all slot reuse is same-wave in-order DS; register anti-deps
// (write sources vs read dests) are sequential in program order.
__device__ __forceinline__ void transpose64(v2f* w, float* sh, int lane) {
    const int  rr = lane & 31;
    const bool lo = lane < 32;
    float* wp = sh + 2 * rr;                       // writer column base
    const int rbase = (rr >> 1) * 66 + (rr & 1);   // reader base
    v2f nv[16];
    // ph(0,0): writers lo publish regs 0..31; readers j<32 take new regs 0..31
    if (lo) {
        #pragma unroll
        for (int k = 0; k < 16; ++k)
            *reinterpret_cast<v2f*>(wp + k * 66) = w[k];
    }
    asm volatile("" ::: "memory");
    if (lo) {
        #pragma unroll
        for (int k = 0; k < 16; ++k) { nv[k][0] = sh[rbase + 4 * k]; nv[k][1] = sh[rbase + 4 * k + 2]; }
    }
    asm volatile("" ::: "memory");
    // ph(0,1): writers lo publish regs 32..63; readers j>=32 take new regs 0..31
    if (lo) {
        #pragma unroll
        for (int k = 0; k < 16; ++k)
            *reinterpret_cast<v2f*>(wp + k * 66) = w[16 + k];
    }
    asm volatile("" ::: "memory");
    if (!lo) {
        #pragma unroll
        for (int k = 0; k < 16; ++k) { nv[k][0] = sh[rbase + 4 * k]; nv[k][1] = sh[rbase + 4 * k + 2]; }
    }
    asm volatile("" ::: "memory");
    // ph(1,0): writers hi publish regs 0..31; readers j<32 take new regs 32..63
    if (!lo) {
        #pragma unroll
        for (int k = 0; k < 16; ++k)
            *reinterpret_cast<v2f*>(wp + k * 66) = w[k];
    }
    asm volatile("" ::: "memory");
    if (lo) {
        #pragma unroll
        for (int k = 0; k < 16; ++k) { w[16 + k][0] = sh[rbase + 4 * k]; w[16 + k][1] = sh[rbase + 4 * k + 2]; }
    }
    asm volatile("" ::: "memory");
    // ph(1,1): writers hi publish regs 32..63; readers j>=32 take new regs 32..63
    if (!lo) {
        #pragma unroll
        for (int k = 0; k < 16; ++k)
            *reinterpret_cast<v2f*>(wp + k * 66) = w[16 + k];
    }
    asm volatile("" ::: "memory");
    if (!lo) {
        #pragma unroll
        for (int k = 0; k < 16; ++k) { w[16 + k][0] = sh[rbase + 4 * k]; w[16 + k][1] = sh[rbase + 4 * k + 2]; }
    }
    asm volatile("" ::: "memory");
    #pragma unroll
    for (int k = 0; k < 16; ++k) w[k] = nv[k];
    asm volatile("" ::: "memory");
}

__device__ __forceinline__ float tanhalf(float ang, float& G) {
    float s, c;
    __sincosf(ang, &s, &c);
    G *= c;
    return s * __builtin_amdgcn_rcpf(c);
}

// layer entering in layout A (theta row T; ends in layout B)
template<int T>
__device__ __forceinline__ void layerA(v2f* w, const float* __restrict__ th,
                                       int lane, float& G, float* sh) {
    regRY<T, 0>(w, tanhalf(0.5f * th[T * NQ + 0], G));
    regRY<T, 1>(w, tanhalf(0.5f * th[T * NQ + 1], G));
    regRY<T, 2>(w, tanhalf(0.5f * th[T * NQ + 2], G));
    regRY<T, 3>(w, tanhalf(0.5f * th[T * NQ + 3], G));
    regRY<T, 4>(w, tanhalf(0.5f * th[T * NQ + 4], G));
    regRY<T, 5>(w, tanhalf(0.5f * th[T * NQ + 5], G));
    transpose64(w, sh, lane);
    regRY<T, 0>(w, tanhalf(0.5f * th[T * NQ + 6],  G));
    regRY<T, 1>(w, tanhalf(0.5f * th[T * NQ + 7],  G));
    regRY<T, 2>(w, tanhalf(0.5f * th[T * NQ + 8],  G));
    regRY<T, 3>(w, tanhalf(0.5f * th[T * NQ + 9],  G));
    regRY<T, 4>(w, tanhalf(0.5f * th[T * NQ + 10], G));
    regRY<T, 5>(w, tanhalf(0.5f * th[T * NQ + 11], G));
    ringB<T>(w, lane);
}

// layer entering in layout B (theta row T; ends in layout A)
template<int T>
__device__ __forceinline__ void layerB(v2f* w, const float* __restrict__ th,
                                       int lane, float& G, float* sh) {
    regRY<T, 0>(w, tanhalf(0.5f * th[T * NQ + 6],  G));
    regRY<T, 1>(w, tanhalf(0.5f * th[T * NQ + 7],  G));
    regRY<T, 2>(w, tanhalf(0.5f * th[T * NQ + 8],  G));
    regRY<T, 3>(w, tanhalf(0.5f * th[T * NQ + 9],  G));
    regRY<T, 4>(w, tanhalf(0.5f * th[T * NQ + 10], G));
    regRY<T, 5>(w, tanhalf(0.5f * th[T * NQ + 11], G));
    transpose64(w, sh, lane);
    regRY<T, 0>(w, tanhalf(0.5f * th[T * NQ + 0], G));
    regRY<T, 1>(w, tanhalf(0.5f * th[T * NQ + 1], G));
    regRY<T, 2>(w, tanhalf(0.5f * th[T * NQ + 2], G));
    regRY<T, 3>(w, tanhalf(0.5f * th[T * NQ + 3], G));
    regRY<T, 4>(w, tanhalf(0.5f * th[T * NQ + 4], G));
    regRY<T, 5>(w, tanhalf(0.5f * th[T * NQ + 5], G));
    ringA<T>(w, lane);
}

__global__ __launch_bounds__(128)
void qc_kernel(const float* __restrict__ x, const float* __restrict__ theta,
               float* __restrict__ out) {
    __shared__ float shbuf[2][1056];   // max slot 15*66 + 63 = 1053
    const int lane = threadIdx.x & 63;
    const int wid  = threadIdx.x >> 6;
    const int b = __builtin_amdgcn_readfirstlane((blockIdx.x << 1) + wid);
    float* sh = &shbuf[wid][0];

    alignas(16) v2f w[32];

    // ---- init in layout A, layer-0 thetas folded: RY(th)RY(x)|0> = RY(x+th)|0>
    float L = 1.0f;
    #pragma unroll
    for (int q = 6; q < NQ; ++q) {
        float s, c;
        __sincosf(0.5f * (x[b * NQ + q] + theta[q]), &s, &c);
        L *= ((lane >> (q - 6)) & 1) ? s : c;
    }
    {
        float s, c;
        __sincosf(0.5f * (x[b * NQ + 0] + theta[0]), &s, &c);
        w[0] = {L * c, L * s};
    }
    #pragma unroll
    for (int q = 1; q < 6; ++q) {
        float s, c;
        __sincosf(0.5f * (x[b * NQ + q] + theta[q]), &s, &c);
        const v2f vs = {s, s}, vc = {c, c};
        #pragma unroll
        for (int k = 0; k < (1 << (q - 1)); ++k) {
            w[k + (1 << (q - 1))] = w[k] * vs;
            w[k]                  = w[k] * vc;
        }
    }

    float G = 1.0f;            // product of cosines over layers 1..3
    ringA<0>(w, lane);         // layer-0 ring (gates folded into init)
    layerA<1>(w, theta, lane, G, sh);   // A -> B
    layerB<2>(w, theta, lane, G, sh);   // B -> A
    layerA<3>(w, theta, lane, G, sh);   // A -> B
    // final: layout B, renaming powers (4,4)

    // ---- epilogue: out[b,q] = G^2 * sum_d v^2 * (1-2 bit_q(d))
    // phys = sig^4(L): L0..3 = phys0..3, L4 = phys4^phys0, L5 = phys5^phys1.
    // comp = phys bit0; w-index bits = phys bits 1..5.  Packed 5-level tree.
    #pragma unroll
    for (int k = 0; k < 32; ++k) w[k] = w[k] * w[k];

    v2f u1[16], c1[16];
    #pragma unroll
    for (int m = 0; m < 16; ++m) {
        u1[m] = w[2 * m] + w[2 * m + 1];
        c1[m] = w[2 * m] - w[2 * m + 1];     // sign: phys1
    }
    v2f u2[8], d2v = {0.f, 0.f};
    #pragma unroll
    for (int m = 0; m < 8; ++m) {
        u2[m] = u1[2 * m] + u1[2 * m + 1];
        d2v  += u1[2 * m] - u1[2 * m + 1];   // sign: phys2
    }
    v2f c2[8];
    #pragma unroll
    for (int m = 0; m < 8; ++m) c2[m] = c1[2 * m] + c1[2 * m + 1];
    v2f u3[4], d3v = {0.f, 0.f};
    #pragma unroll
    for (int m = 0; m < 4; ++m) {
        u3[m] = u2[2 * m] + u2[2 * m + 1];
        d3v  += u2[2 * m] - u2[2 * m + 1];   // sign: phys3
    }
    v2f c3[4];
    #pragma unroll
    for (int m = 0; m < 4; ++m) c3[m] = c2[2 * m] + c2[2 * m + 1];
    v2f u4[2], c4[2];
    u4[0] = u3[0] + u3[1]; u4[1] = u3[2] + u3[3];
    v2f d4v = (u3[0] - u3[1]) + (u3[2] - u3[3]);   // sign: phys4
    c4[0] = c3[0] + c3[1]; c4[1] = c3[2] + c3[3];
    v2f U  = u4[0] + u4[1];
    v2f cS = c4[0] + c4[1];                  // sign: phys1
    v2f cD = c4[0] - c4[1];                  // sign: phys1^phys5

    const float tot = U[0] + U[1];
    float Dq[6];
    Dq[0] = U[0] - U[1];
    Dq[1] = cS[0] + cS[1];
    Dq[2] = d2v[0] + d2v[1];
    Dq[3] = d3v[0] + d3v[1];
    Dq[4] = d4v[0] - d4v[1];                 // ^phys0 via comp sign
    Dq[5] = cD[0] + cD[1];

    float res[NQ];
    res[0] = wave_red<rowmask6(0, 4)>(tot);  // lane qubits 0..5
    res[1] = wave_red<rowmask6(1, 4)>(tot);
    res[2] = wave_red<rowmask6(2, 4)>(tot);
    res[3] = wave_red<rowmask6(3, 4)>(tot);
    res[4] = wave_red<rowmask6(4, 4)>(tot);
    res[5] = wave_red<rowmask6(5, 4)>(tot);
    #pragma unroll
    for (int j = 0; j < 6; ++j) res[6 + j] = wave_red<0>(Dq[j]);  // reg qubits

    float myres = res[0];
    #pragma unroll
    for (int q = 1; q < NQ; ++q) myres = (lane == q) ? res[q] : myres;
    myres *= G * G;
    if (lane < NQ) out[b * NQ + lane] = myres;
}

extern "C" void kernel_launch(void* const* d_in, const int* in_sizes, int n_in,
                              void* d_out, int out_size, void* d_ws, size_t ws_size,
                              hipStream_t stream) {
    const float* x     = (const float*)d_in[0];
    const float* theta = (const float*)d_in[1];
    float* out = (float*)d_out;
    dim3 grid(BATCH / 2), block(128);
    qc_kernel<<<grid, block, 0, stream>>>(x, theta, out);
}

// Round 12
// 44.623 us; speedup vs baseline: 1.1710x; 1.1710x over previous
//
#include <hip/hip_runtime.h>

#define NQ    12
#define BATCH 8192

typedef float v2f __attribute__((ext_vector_type(2)));

// ---------------------------------------------------------------------------
// One wave = one batch element's 4096-dim real state (imag identically 0).
// Layout A: lane bits = qubits 6..11, reg bits = qubits 0..5
// Layout B: lane bits = qubits 0..5,  reg bits = qubits 6..11
// Per layer: 6 reg-gates, LDS transpose (R10 2-phase pair-slot, S=66),
// 6 reg-gates, ring boundary CNOTs; ring renamings (sig powers) deferred via
// compile-time index renaming.  RY in tan form; G = prod cos folded into the
// epilogue as G^2.  State float2[32], gates via v_pk_fma_f32.
// This round: theta trig vectorized (one wave-wide sincos on lanes 12..47 +
// readlane broadcast; G via wave-product); 256-thread blocks (4 waves).
// ---------------------------------------------------------------------------

constexpr int sig6(int x)            { return (x ^ (x << 1)) & 63; }
constexpr int sigpow6(int x, int t)  { return t == 0 ? x : sigpow6(sig6(x), t - 1); }
constexpr int rowmask6(int j, int t) {        // bit_j(sig^-t(p)) = par(p & m)
    int tt = (8 - (t % 8)) % 8;
    int m = 0;
    for (int i = 0; i < 6; ++i)
        if ((sigpow6(1 << i, tt) >> j) & 1) m |= 1 << i;
    return m;
}
constexpr bool par6(int x) { return (__builtin_popcount(x & 63) & 1) != 0; }

#define VAT(w, i) w[(i) >> 1][(i) & 1]

// ---- cross-lane helpers ---------------------------------------------------
template<int C>
__device__ __forceinline__ float dppf(float x) {
    return __int_as_float(__builtin_amdgcn_mov_dpp(__float_as_int(x), C, 0xF, 0xF, true));
}

template<int M>
__device__ __forceinline__ float shx(float x) {
    static_assert(M > 0 && M < 64, "mask");
    constexpr int lo = M & 31;
    float y = x;
    if constexpr (lo == 1)       y = dppf<0xB1>(y);
    else if constexpr (lo == 2)  y = dppf<0x4E>(y);
    else if constexpr (lo == 3)  y = dppf<0x1B>(y);
    else if constexpr (lo == 7)  y = dppf<0x141>(y);
    else if constexpr (lo == 15) y = dppf<0x140>(y);
    else if constexpr (lo != 0)
        y = __int_as_float(__builtin_amdgcn_ds_swizzle(__float_as_int(y),
                                                       0x1F | (lo << 10)));
    if constexpr ((M & 32) != 0) {
        int yi = __float_as_int(y);
        auto p = __builtin_amdgcn_permlane32_swap(yi, yi, false, false);
        y = (__int_as_float(p[0]) + __int_as_float(p[1])) - y;
    }
    return y;
}

// signed butterfly: sum_l (-1)^par(l&M) x_l (writing lanes 0..11 sign-positive)
template<int M>
__device__ __forceinline__ float wave_red(float x) {
    { float o = dppf<0xB1>(x); x = (M & 1)  ? x - o : x + o; }
    { float o = dppf<0x4E>(x); x = (M & 2)  ? x - o : x + o; }
    { float o = __int_as_float(__builtin_amdgcn_ds_swizzle(__float_as_int(x), 0x1F | (4  << 10))); x = (M & 4)  ? x - o : x + o; }
    { float o = __int_as_float(__builtin_amdgcn_ds_swizzle(__float_as_int(x), 0x1F | (8  << 10))); x = (M & 8)  ? x - o : x + o; }
    { float o = __int_as_float(__builtin_amdgcn_ds_swizzle(__float_as_int(x), 0x1F | (16 << 10))); x = (M & 16) ? x - o : x + o; }
    int xi = __float_as_int(x);
    auto p = __builtin_amdgcn_permlane32_swap(xi, xi, false, false);
    float s = __int_as_float(p[0]) + __int_as_float(p[1]);
    return (M & 32) ? (2.0f * x - s) : s;
}

__device__ __forceinline__ float wave_prod(float x) {
    x *= dppf<0xB1>(x);
    x *= dppf<0x4E>(x);
    x *= __int_as_float(__builtin_amdgcn_ds_swizzle(__float_as_int(x), 0x1F | (4  << 10)));
    x *= __int_as_float(__builtin_amdgcn_ds_swizzle(__float_as_int(x), 0x1F | (8  << 10)));
    x *= __int_as_float(__builtin_amdgcn_ds_swizzle(__float_as_int(x), 0x1F | (16 << 10)));
    int xi = __float_as_int(x);
    auto p = __builtin_amdgcn_permlane32_swap(xi, xi, false, false);
    return __int_as_float(p[0]) * __int_as_float(p[1]);
}

__device__ __forceinline__ float rl(float v, int l) {
    return __int_as_float(__builtin_amdgcn_readlane(__float_as_int(v), l));
}

// ---- packed tan-form RY on reg qubit-bit Q, renaming sig^T ----------------
template<int T, int Q>
__device__ __forceinline__ void regRY(v2f* w, float t) {
    constexpr int D = sigpow6(1 << Q, T);   // physical partner xor
    const v2f tMM = {-t, -t}, tPP = {t, t}, tMP = {-t, t}, tPM = {t, -t};
    if constexpr (Q == 0) {
        constexpr int K = D >> 1;           // D odd: comp-swapped partner
        #pragma unroll
        for (int k = 0; k < 32; ++k) {
            const int k2 = k ^ K;
            if (k2 < k) continue;
            v2f a = w[k], b = w[k2];
            v2f sb = {b[1], b[0]}, sa = {a[1], a[0]};
            w[k]  = __builtin_elementwise_fma(tMP, sb, a);
            w[k2] = __builtin_elementwise_fma(tMP, sa, b);
        }
    } else {
        constexpr int K  = D >> 1;          // D even: comps aligned
        constexpr int RM = rowmask6(Q, T);
        #pragma unroll
        for (int k = 0; k < 32; ++k) {
            const int k2 = k ^ K;
            if (k2 < k) continue;
            const bool p = par6((2 * k) & RM);
            if constexpr (RM & 1) {
                v2f a = w[k], b = w[k2];
                const v2f tk  = p ? tPM : tMP;
                const v2f tk2 = p ? tMP : tPM;
                w[k]  = __builtin_elementwise_fma(tk,  b, a);
                w[k2] = __builtin_elementwise_fma(tk2, a, b);
            } else {
                if (p) {
                    v2f a = w[k2], b = w[k];
                    w[k2] = __builtin_elementwise_fma(tMM, b, a);
                    w[k]  = __builtin_elementwise_fma(tPP, a, b);
                } else {
                    v2f a = w[k], b = w[k2];
                    w[k]  = __builtin_elementwise_fma(tMM, b, a);
                    w[k2] = __builtin_elementwise_fma(tPP, a, b);
                }
            }
        }
    }
}

// ---- ring boundary CNOTs --------------------------------------------------
template<int T>          // layout A CNOT(5,6): reg bit5 controls lane xor
__device__ __forceinline__ void c56A(v2f* w) {
    constexpr int ML = sigpow6(1, T);
    #pragma unroll
    for (int r = 32; r < 64; ++r) {
        const int pr = sigpow6(r, T + 1);
        VAT(w, pr) = shx<ML>(VAT(w, pr));
    }
}
template<int T>          // layout A CNOT(11,0): lane bit5 controls reg swap
__device__ __forceinline__ void c110A(v2f* w, int lane) {
    const bool cond = par6(lane & rowmask6(5, T + 1));
    constexpr int D = sigpow6(1, T + 1);
    #pragma unroll
    for (int r0 = 0; r0 < 64; r0 += 2) {
        const int a0 = sigpow6(r0, T + 1);
        const int a1 = a0 ^ D;
        float x0 = VAT(w, a0), x1 = VAT(w, a1);
        VAT(w, a0) = cond ? x1 : x0;
        VAT(w, a1) = cond ? x0 : x1;
    }
}
template<int T>          // layout B CNOT(5,6): lane bit5 controls reg swap
__device__ __forceinline__ void c56B(v2f* w, int lane) {
    const bool cond = par6(lane & rowmask6(5, T + 1));
    constexpr int D = sigpow6(1, T);
    #pragma unroll
    for (int r0 = 0; r0 < 64; r0 += 2) {
        const int a0 = sigpow6(r0, T);
        const int a1 = a0 ^ D;
        float x0 = VAT(w, a0), x1 = VAT(w, a1);
        VAT(w, a0) = cond ? x1 : x0;
        VAT(w, a1) = cond ? x0 : x1;
    }
}
template<int T>          // layout B CNOT(11,0): reg bit5 controls lane xor
__device__ __forceinline__ void c110B(v2f* w) {
    constexpr int ML = sigpow6(1, T + 1);
    #pragma unroll
    for (int r = 32; r < 64; ++r) {
        const int pr = sigpow6(r, T + 1);
        VAT(w, pr) = shx<ML>(VAT(w, pr));
    }
}
template<int T>
__device__ __forceinline__ void ringA(v2f* w, int lane) { c56A<T>(w); c110A<T>(w, lane); }
template<int T>
__device__ __forceinline__ void ringB(v2f* w, int lane) { c56B<T>(w, lane); c110B<T>(w); }

// ---- lane<->reg transpose, 2-phase, pair-slot layout (S = 66, R10) --------
__device__ __forceinline__ void transpose64(v2f* w, float* sh, int lane) {
    const int row = lane & 31;
    const int rm  = (lane >> 1) * 66 + (lane & 1);
    v2f nv[16];
    if (lane < 32) {
        #pragma unroll
        for (int k = 0; k < 32; ++k)
            *reinterpret_cast<v2f*>(sh + row * 2 + k * 66) = w[k];
    }
    asm volatile("" ::: "memory");
    #pragma unroll
    for (int k = 0; k < 16; ++k) {
        nv[k][0] = sh[rm + 4 * k];
        nv[k][1] = sh[rm + 4 * k + 2];
    }
    asm volatile("" ::: "memory");
    if (lane >= 32) {
        #pragma unroll
        for (int k = 0; k < 32; ++k)
            *reinterpret_cast<v2f*>(sh + row * 2 + k * 66) = w[k];
    }
    asm volatile("" ::: "memory");
    #pragma unroll
    for (int k = 0; k < 16; ++k) {
        w[16 + k][0] = sh[rm + 4 * k];
        w[16 + k][1] = sh[rm + 4 * k + 2];
    }
    #pragma unroll
    for (int k = 0; k < 16; ++k) w[k] = nv[k];
    asm volatile("" ::: "memory");
}

// layer entering in layout A (theta row T; ends in layout B)
template<int T>
__device__ __forceinline__ void layerA(v2f* w, int lane, float* sh, float t_l) {
    regRY<T, 0>(w, rl(t_l, T * NQ + 0));
    regRY<T, 1>(w, rl(t_l, T * NQ + 1));
    regRY<T, 2>(w, rl(t_l, T * NQ + 2));
    regRY<T, 3>(w, rl(t_l, T * NQ + 3));
    regRY<T, 4>(w, rl(t_l, T * NQ + 4));
    regRY<T, 5>(w, rl(t_l, T * NQ + 5));
    transpose64(w, sh, lane);
    regRY<T, 0>(w, rl(t_l, T * NQ + 6));
    regRY<T, 1>(w, rl(t_l, T * NQ + 7));
    regRY<T, 2>(w, rl(t_l, T * NQ + 8));
    regRY<T, 3>(w, rl(t_l, T * NQ + 9));
    regRY<T, 4>(w, rl(t_l, T * NQ + 10));
    regRY<T, 5>(w, rl(t_l, T * NQ + 11));
    ringB<T>(w, lane);
}

// layer entering in layout B (theta row T; ends in layout A)
template<int T>
__device__ __forceinline__ void layerB(v2f* w, int lane, float* sh, float t_l) {
    regRY<T, 0>(w, rl(t_l, T * NQ + 6));
    regRY<T, 1>(w, rl(t_l, T * NQ + 7));
    regRY<T, 2>(w, rl(t_l, T * NQ + 8));
    regRY<T, 3>(w, rl(t_l, T * NQ + 9));
    regRY<T, 4>(w, rl(t_l, T * NQ + 10));
    regRY<T, 5>(w, rl(t_l, T * NQ + 11));
    transpose64(w, sh, lane);
    regRY<T, 0>(w, rl(t_l, T * NQ + 0));
    regRY<T, 1>(w, rl(t_l, T * NQ + 1));
    regRY<T, 2>(w, rl(t_l, T * NQ + 2));
    regRY<T, 3>(w, rl(t_l, T * NQ + 3));
    regRY<T, 4>(w, rl(t_l, T * NQ + 4));
    regRY<T, 5>(w, rl(t_l, T * NQ + 5));
    ringA<T>(w, lane);
}

__global__ __launch_bounds__(256)
void qc_kernel(const float* __restrict__ x, const float* __restrict__ theta,
               float* __restrict__ out) {
    __shared__ float shbuf[4][2112];   // max slot 31*66+63 = 2109, per wave
    const int lane = threadIdx.x & 63;
    const int wid  = threadIdx.x >> 6;
    const int b = __builtin_amdgcn_readfirstlane((blockIdx.x << 2) + wid);
    float* sh = &shbuf[wid][0];

    // ---- vectorized theta trig: lane q holds tan(theta[q]/2); G = prod cos
    // over lanes 12..47 (layers 1..3; layer 0 is folded into init).
    const float th_l = theta[lane < 48 ? lane : 0];
    float s5, c5;
    __sincosf(0.5f * th_l, &s5, &c5);
    const float t_l = s5 * __builtin_amdgcn_rcpf(c5);
    const float G = wave_prod((lane >= 12 && lane < 48) ? c5 : 1.0f);

    alignas(16) v2f w[32];

    // ---- init in layout A, layer-0 thetas folded: RY(th)RY(x)|0> = RY(x+th)|0>
    float L = 1.0f;
    #pragma unroll
    for (int q = 6; q < NQ; ++q) {
        float s, c;
        __sincosf(0.5f * (x[b * NQ + q] + rl(th_l, q)), &s, &c);
        L *= ((lane >> (q - 6)) & 1) ? s : c;
    }
    {
        float s, c;
        __sincosf(0.5f * (x[b * NQ + 0] + rl(th_l, 0)), &s, &c);
        w[0] = {L * c, L * s};
    }
    #pragma unroll
    for (int q = 1; q < 6; ++q) {
        float s, c;
        __sincosf(0.5f * (x[b * NQ + q] + rl(th_l, q)), &s, &c);
        const v2f vs = {s, s}, vc = {c, c};
        #pragma unroll
        for (int k = 0; k < (1 << (q - 1)); ++k) {
            w[k + (1 << (q - 1))] = w[k] * vs;
            w[k]                  = w[k] * vc;
        }
    }

    ringA<0>(w, lane);         // layer-0 ring (gates folded into init)
    layerA<1>(w, lane, sh, t_l);   // A -> B
    layerB<2>(w, lane, sh, t_l);   // B -> A
    layerA<3>(w, lane, sh, t_l);   // A -> B
    // final: layout B, renaming powers (4,4)

    // ---- epilogue: out[b,q] = G^2 * sum_d v^2 * (1-2 bit_q(d))
    // phys = sig^4(L): comp = phys bit0; w-index bits = phys bits 1..5.
    #pragma unroll
    for (int k = 0; k < 32; ++k) w[k] = w[k] * w[k];

    v2f u1[16], c1[16];
    #pragma unroll
    for (int m = 0; m < 16; ++m) {
        u1[m] = w[2 * m] + w[2 * m + 1];
        c1[m] = w[2 * m] - w[2 * m + 1];     // sign: phys1
    }
    v2f u2[8], d2v = {0.f, 0.f};
    #pragma unroll
    for (int m = 0; m < 8; ++m) {
        u2[m] = u1[2 * m] + u1[2 * m + 1];
        d2v  += u1[2 * m] - u1[2 * m + 1];   // sign: phys2
    }
    v2f c2[8];
    #pragma unroll
    for (int m = 0; m < 8; ++m) c2[m] = c1[2 * m] + c1[2 * m + 1];
    v2f u3[4], d3v = {0.f, 0.f};
    #pragma unroll
    for (int m = 0; m < 4; ++m) {
        u3[m] = u2[2 * m] + u2[2 * m + 1];
        d3v  += u2[2 * m] - u2[2 * m + 1];   // sign: phys3
    }
    v2f c3[4];
    #pragma unroll
    for (int m = 0; m < 4; ++m) c3[m] = c2[2 * m] + c2[2 * m + 1];
    v2f u4[2], c4[2];
    u4[0] = u3[0] + u3[1]; u4[1] = u3[2] + u3[3];
    v2f d4v = (u3[0] - u3[1]) + (u3[2] - u3[3]);   // sign: phys4
    c4[0] = c3[0] + c3[1]; c4[1] = c3[2] + c3[3];
    v2f U  = u4[0] + u4[1];
    v2f cS = c4[0] + c4[1];                  // sign: phys1
    v2f cD = c4[0] - c4[1];                  // sign: phys1^phys5

    const float tot = U[0] + U[1];
    float Dq[6];
    Dq[0] = U[0] - U[1];
    Dq[1] = cS[0] + cS[1];
    Dq[2] = d2v[0] + d2v[1];
    Dq[3] = d3v[0] + d3v[1];
    Dq[4] = d4v[0] - d4v[1];                 // ^phys0 via comp sign
    Dq[5] = cD[0] + cD[1];

    float res[NQ];
    res[0] = wave_red<rowmask6(0, 4)>(tot);  // lane qubits 0..5
    res[1] = wave_red<rowmask6(1, 4)>(tot);
    res[2] = wave_red<rowmask6(2, 4)>(tot);
    res[3] = wave_red<rowmask6(3, 4)>(tot);
    res[4] = wave_red<rowmask6(4, 4)>(tot);
    res[5] = wave_red<rowmask6(5, 4)>(tot);
    #pragma unroll
    for (int j = 0; j < 6; ++j) res[6 + j] = wave_red<0>(Dq[j]);  // reg qubits

    float myres = res[0];
    #pragma unroll
    for (int q = 1; q < NQ; ++q) myres = (lane == q) ? res[q] : myres;
    myres *= G * G;
    if (lane < NQ) out[b * NQ + lane] = myres;
}

extern "C" void kernel_launch(void* const* d_in, const int* in_sizes, int n_in,
                              void* d_out, int out_size, void* d_ws, size_t ws_size,
                              hipStream_t stream) {
    const float* x     = (const float*)d_in[0];
    const float* theta = (const float*)d_in[1];
    float* out = (float*)d_out;
    dim3 grid(BATCH / 4), block(256);
    qc_kernel<<<grid, block, 0, stream>>>(x, theta, out);
}